// Round 14
// baseline (861.590 us; speedup 1.0000x reference)
//
#include <hip/hip_runtime.h>

#define NN 50000
#define EE 1000000
#define HALF 25000

__device__ __forceinline__ float wsum(float v){
#pragma unroll
  for(int m=1;m<64;m<<=1) v += __shfl_xor(v,m,64);
  return v;
}
__device__ __forceinline__ unsigned encf(float f){
  unsigned u = __float_as_uint(f);
  return (u & 0x80000000u) ? ~u : (u | 0x80000000u);
}
__device__ __forceinline__ float decf(unsigned u){
  u = (u & 0x80000000u) ? (u & 0x7fffffffu) : ~u;
  return __uint_as_float(u);
}

__global__ __launch_bounds__(256) void zero_k(int* counts, int* cursor, unsigned* mx){
  int i = blockIdx.x*blockDim.x + threadIdx.x;
  if(i < NN){ counts[i] = 0; cursor[i] = 0; }
  if(i < 64) mx[i] = 0u;
}

__global__ __launch_bounds__(64) void cvec_k(const float* __restrict__ gat_W, const float* __restrict__ gat_a,
                                             float* __restrict__ cdir){
  int h = blockIdx.x, k = threadIdx.x;
  const float* W = gat_W + (size_t)h*64*64;
  const float* a = gat_a + (size_t)h*192;
  float cs = 0.f, ct = 0.f;
#pragma unroll
  for(int j=0;j<64;j++){ float wv = W[k*64+j]; cs += wv*a[j]; ct += wv*a[64+j]; }
  cdir[h*64 + k]       = cs;
  cdir[512 + h*64 + k] = ct;
}

// node MLP fused with per-head projections ps8/pt8
__global__ __launch_bounds__(256) void node_mlp(const float* __restrict__ X, const float* __restrict__ w,
                                                const float* __restrict__ b, const float* __restrict__ g,
                                                const float* __restrict__ beta, const float* __restrict__ cdir,
                                                float* __restrict__ x, float* __restrict__ ps8,
                                                float* __restrict__ pt8){
  int wid  = (blockIdx.x*blockDim.x + threadIdx.x) >> 6;
  int lane = threadIdx.x & 63;
  if(wid >= NN) return;
  float acc = b[lane];
#pragma unroll
  for(int k=0;k<16;k++) acc += X[wid*16+k] * w[k*64+lane];
  float mu  = wsum(acc) * (1.0f/64.0f);
  float d   = acc - mu;
  float var = wsum(d*d) * (1.0f/64.0f);
  float y   = d * rsqrtf(var + 1e-5f) * g[lane] + beta[lane];
  float xv  = fmaxf(y, 0.0f);
  x[(size_t)wid*64 + lane] = xv;
#pragma unroll 1
  for(int h=0;h<8;h++){
    float a = wsum(xv * cdir[h*64+lane]);
    float c = wsum(xv * cdir[512 + h*64+lane]);
    if(lane == 0){ ps8[wid*8+h] = a; pt8[wid*8+h] = c; }
  }
}

__global__ __launch_bounds__(256) void hist_k(const int* __restrict__ src, int* __restrict__ counts){
  int e = blockIdx.x*blockDim.x + threadIdx.x;
  if(e < EE){
    int s = src[e];
    if((unsigned)s >= NN) s = 0;
    atomicAdd(&counts[s], 1);
  }
}

__global__ __launch_bounds__(256) void scan1_k(const int* __restrict__ counts, int* __restrict__ bsum){
  int i = blockIdx.x*256 + threadIdx.x;
  int v = (i < NN) ? counts[i] : 0;
  int s = v;
#pragma unroll
  for(int m=1;m<64;m<<=1) s += __shfl_xor(s,m,64);
  __shared__ int sm[4];
  if((threadIdx.x & 63) == 0) sm[threadIdx.x>>6] = s;
  __syncthreads();
  if(threadIdx.x == 0) bsum[blockIdx.x] = sm[0]+sm[1]+sm[2]+sm[3];
}

__global__ __launch_bounds__(256) void scan2_k(const int* __restrict__ bsum, int* __restrict__ bpre,
                                               int* __restrict__ offs){
  const int NB = (NN + 255)/256;
  int t = threadIdx.x;
  __shared__ int sm[256];
  int v = (t < NB) ? bsum[t] : 0;
  sm[t] = v; __syncthreads();
  for(int off=1; off<256; off<<=1){
    int u = (t >= off) ? sm[t-off] : 0;
    __syncthreads();
    sm[t] += u;
    __syncthreads();
  }
  if(t < NB) bpre[t] = sm[t] - v;
  if(t == 0) offs[NN] = EE;
}

__global__ __launch_bounds__(256) void scan3_k(const int* __restrict__ counts, const int* __restrict__ bpre,
                                               int* __restrict__ offs){
  int i = blockIdx.x*256 + threadIdx.x;
  int t = threadIdx.x;
  __shared__ int sm[256];
  int v = (i < NN) ? counts[i] : 0;
  sm[t] = v; __syncthreads();
  for(int off=1; off<256; off<<=1){
    int u = (t >= off) ? sm[t-off] : 0;
    __syncthreads();
    sm[t] += u;
    __syncthreads();
  }
  if(i < NN) offs[i] = bpre[blockIdx.x] + sm[t] - v;
}

__global__ __launch_bounds__(256) void scatter_k(const int* __restrict__ src, const int* __restrict__ tgt,
                                                 const int* __restrict__ offs, int* __restrict__ cursor,
                                                 int* __restrict__ rank, int* __restrict__ tgt_s,
                                                 int* __restrict__ src_s){
  int e = blockIdx.x*blockDim.x + threadIdx.x;
  if(e < EE){
    int s = src[e];
    if((unsigned)s >= NN) s = 0;
    int pos = offs[s] + atomicAdd(&cursor[s], 1);
    rank[e] = pos;
    int t = tgt[e];
    if((unsigned)t >= NN) t = 0;
    tgt_s[pos] = t;
    src_s[pos] = s;
  }
}

// edge MLP v2 (validated R10): LDS-staged weights
__global__ __launch_bounds__(256) void edge_mlp_q(const int* __restrict__ rank, const float* __restrict__ ea,
                                                  const float* __restrict__ w, const float* __restrict__ b,
                                                  const float* __restrict__ g, const float* __restrict__ beta,
                                                  const float* __restrict__ gat_a, const float* __restrict__ out_a,
                                                  float* __restrict__ q8, float* __restrict__ q_out){
  __shared__ float wle[512];
  __shared__ float ble[64], gle[64], bbe[64];
  __shared__ float ale[64*12];
  int tid = threadIdx.x;
  for(int idx=tid; idx<512; idx+=256){ int j=idx>>3, k=idx&7; wle[idx] = w[k*64+j]; }
  if(tid < 64){
    ble[tid] = b[tid]; gle[tid] = g[tid]; bbe[tid] = beta[tid];
#pragma unroll
    for(int r=0;r<8;r++) ale[tid*12+r] = gat_a[r*192 + 128 + tid];
    ale[tid*12+8] = out_a[128 + tid];
  }
  __syncthreads();
  int e = blockIdx.x*blockDim.x + tid;
  if(e >= EE) return;
  float4 ia = ((const float4*)ea)[(size_t)e*2];
  float4 ib = ((const float4*)ea)[(size_t)e*2+1];
  float y[64];
#pragma unroll
  for(int j=0;j<64;j++){
    float4 w0 = *(const float4*)&wle[j*8];
    float4 w1 = *(const float4*)&wle[j*8+4];
    float acc = ble[j];
    acc = fmaf(ia.x,w0.x, fmaf(ia.y,w0.y, fmaf(ia.z,w0.z, fmaf(ia.w,w0.w, acc))));
    acc = fmaf(ib.x,w1.x, fmaf(ib.y,w1.y, fmaf(ib.z,w1.z, fmaf(ib.w,w1.w, acc))));
    y[j] = acc;
  }
  float mu = 0.f;
#pragma unroll
  for(int j=0;j<64;j++) mu += y[j];
  mu *= (1.0f/64.0f);
  float var = 0.f;
#pragma unroll
  for(int j=0;j<64;j++){ float d = y[j]-mu; var += d*d; }
  var *= (1.0f/64.0f);
  float inv = rsqrtf(var + 1e-5f);
#pragma unroll
  for(int j=0;j<64;j++) y[j] = fmaxf((y[j]-mu)*inv*gle[j] + bbe[j], 0.0f);
  float qv[9];
#pragma unroll
  for(int r=0;r<9;r++) qv[r] = 0.f;
#pragma unroll
  for(int j=0;j<64;j++){
    float4 a0 = *(const float4*)&ale[j*12];
    float4 a1 = *(const float4*)&ale[j*12+4];
    float a8  = ale[j*12+8];
    float yj = y[j];
    qv[0]=fmaf(yj,a0.x,qv[0]); qv[1]=fmaf(yj,a0.y,qv[1]); qv[2]=fmaf(yj,a0.z,qv[2]); qv[3]=fmaf(yj,a0.w,qv[3]);
    qv[4]=fmaf(yj,a1.x,qv[4]); qv[5]=fmaf(yj,a1.y,qv[5]); qv[6]=fmaf(yj,a1.z,qv[6]); qv[7]=fmaf(yj,a1.w,qv[7]);
    qv[8]=fmaf(yj,a8 ,qv[8]);
  }
  int r = rank[e];
  ((float4*)q8)[(size_t)r*2]   = make_float4(qv[0],qv[1],qv[2],qv[3]);
  ((float4*)q8)[(size_t)r*2+1] = make_float4(qv[4],qv[5],qv[6],qv[7]);
  q_out[r] = qv[8];
}

__global__ __launch_bounds__(256) void maxq_k(const float* __restrict__ q8, const float* __restrict__ q_out,
                                              unsigned* __restrict__ mx){
  float m[9];
#pragma unroll
  for(int r=0;r<9;r++) m[r] = -3.0e38f;
  for(int i = blockIdx.x*256 + threadIdx.x; i < EE; i += gridDim.x*256){
    float4 a = ((const float4*)q8)[(size_t)i*2];
    float4 c = ((const float4*)q8)[(size_t)i*2+1];
    m[0]=fmaxf(m[0],a.x); m[1]=fmaxf(m[1],a.y); m[2]=fmaxf(m[2],a.z); m[3]=fmaxf(m[3],a.w);
    m[4]=fmaxf(m[4],c.x); m[5]=fmaxf(m[5],c.y); m[6]=fmaxf(m[6],c.z); m[7]=fmaxf(m[7],c.w);
    m[8]=fmaxf(m[8], q_out[i]);
  }
#pragma unroll
  for(int r=0;r<9;r++)
#pragma unroll
    for(int msk=1;msk<64;msk<<=1) m[r] = fmaxf(m[r], __shfl_xor(m[r],msk,64));
  __shared__ float sm[4][9];
  int wv = threadIdx.x>>6, lane = threadIdx.x&63;
  if(lane == 0){
#pragma unroll
    for(int r=0;r<9;r++) sm[wv][r] = m[r];
  }
  __syncthreads();
  if(threadIdx.x < 9){
    int r = threadIdx.x;
    float v = fmaxf(fmaxf(sm[0][r],sm[1][r]), fmaxf(sm[2][r],sm[3][r]));
    atomicMax(&mx[r], encf(v));
  }
}

__global__ __launch_bounds__(256) void maxp_k(const float* __restrict__ ps8, const float* __restrict__ pt8,
                                              unsigned* __restrict__ mx){
  float m[16];
#pragma unroll
  for(int r=0;r<16;r++) m[r] = -3.0e38f;
  for(int i = blockIdx.x*256 + threadIdx.x; i < NN; i += gridDim.x*256){
    float4 a = ((const float4*)ps8)[(size_t)i*2];
    float4 c = ((const float4*)ps8)[(size_t)i*2+1];
    float4 d = ((const float4*)pt8)[(size_t)i*2];
    float4 e = ((const float4*)pt8)[(size_t)i*2+1];
    m[0]=fmaxf(m[0],a.x); m[1]=fmaxf(m[1],a.y); m[2]=fmaxf(m[2],a.z); m[3]=fmaxf(m[3],a.w);
    m[4]=fmaxf(m[4],c.x); m[5]=fmaxf(m[5],c.y); m[6]=fmaxf(m[6],c.z); m[7]=fmaxf(m[7],c.w);
    m[8]=fmaxf(m[8],d.x); m[9]=fmaxf(m[9],d.y); m[10]=fmaxf(m[10],d.z); m[11]=fmaxf(m[11],d.w);
    m[12]=fmaxf(m[12],e.x); m[13]=fmaxf(m[13],e.y); m[14]=fmaxf(m[14],e.z); m[15]=fmaxf(m[15],e.w);
  }
#pragma unroll
  for(int r=0;r<16;r++)
#pragma unroll
    for(int msk=1;msk<64;msk<<=1) m[r] = fmaxf(m[r], __shfl_xor(m[r],msk,64));
  __shared__ float sm[4][16];
  int wv = threadIdx.x>>6, lane = threadIdx.x&63;
  if(lane == 0){
#pragma unroll
    for(int r=0;r<16;r++) sm[wv][r] = m[r];
  }
  __syncthreads();
  if(threadIdx.x < 16){
    int r = threadIdx.x;
    float v = fmaxf(fmaxf(sm[0][r],sm[1][r]), fmaxf(sm[2][r],sm[3][r]));
    atomicMax(&mx[16+r], encf(v));
  }
}

__global__ __launch_bounds__(256) void maxpo_k(const float* __restrict__ ps_o, const float* __restrict__ pt_o,
                                               unsigned* __restrict__ mx){
  float m0 = -3.0e38f, m1 = -3.0e38f;
  for(int i = blockIdx.x*256 + threadIdx.x; i < NN; i += gridDim.x*256){
    m0 = fmaxf(m0, ps_o[i]); m1 = fmaxf(m1, pt_o[i]);
  }
#pragma unroll
  for(int msk=1;msk<64;msk<<=1){ m0=fmaxf(m0,__shfl_xor(m0,msk,64)); m1=fmaxf(m1,__shfl_xor(m1,msk,64)); }
  __shared__ float sm[4][2];
  int wv = threadIdx.x>>6, lane = threadIdx.x&63;
  if(lane == 0){ sm[wv][0]=m0; sm[wv][1]=m1; }
  __syncthreads();
  if(threadIdx.x < 2){
    int r = threadIdx.x;
    float v = fmaxf(fmaxf(sm[0][r],sm[1][r]), fmaxf(sm[2][r],sm[3][r]));
    atomicMax(&mx[32+r], encf(v));
  }
}

__global__ __launch_bounds__(256) void score_k(const int* __restrict__ src_s, const int* __restrict__ tgt_s,
                                               const float* __restrict__ ps8, const float* __restrict__ pt8,
                                               const unsigned* __restrict__ mx, float* __restrict__ q8){
  int i = blockIdx.x*256 + threadIdx.x;
  if(i >= EE) return;
  int s = src_s[i], t = tgt_s[i];
  float4 qa = ((const float4*)q8)[(size_t)i*2];
  float4 qb = ((const float4*)q8)[(size_t)i*2+1];
  float4 sa = ((const float4*)ps8)[(size_t)s*2];
  float4 sb = ((const float4*)ps8)[(size_t)s*2+1];
  float4 ta = ((const float4*)pt8)[(size_t)t*2];
  float4 tb = ((const float4*)pt8)[(size_t)t*2+1];
  float sv[8] = {qa.x+sa.x+ta.x, qa.y+sa.y+ta.y, qa.z+sa.z+ta.z, qa.w+sa.w+ta.w,
                 qb.x+sb.x+tb.x, qb.y+sb.y+tb.y, qb.z+sb.z+tb.z, qb.w+sb.w+tb.w};
  float wv[8];
#pragma unroll
  for(int h=0;h<8;h++){
    float B = decf(mx[h]) + decf(mx[16+h]) + decf(mx[24+h]);
    float M = (B > 0.f) ? B : 0.01f*B;
    float x = sv[h];
    x = (x > 0.f) ? x : 0.01f*x;
    wv[h] = __expf(x - M);
  }
  ((float4*)q8)[(size_t)i*2]   = make_float4(wv[0],wv[1],wv[2],wv[3]);
  ((float4*)q8)[(size_t)i*2+1] = make_float4(wv[4],wv[5],wv[6],wv[7]);
}

__global__ __launch_bounds__(256) void score_out_k(const int* __restrict__ src_s, const int* __restrict__ tgt_s,
                                                   const float* __restrict__ ps_o, const float* __restrict__ pt_o,
                                                   const unsigned* __restrict__ mx, float* __restrict__ q_out){
  int i = blockIdx.x*256 + threadIdx.x;
  if(i >= EE) return;
  float B = decf(mx[8]) + decf(mx[32]) + decf(mx[33]);
  float M = (B > 0.f) ? B : 0.01f*B;
  float x = ps_o[src_s[i]] + pt_o[tgt_s[i]] + q_out[i];
  x = (x > 0.f) ? x : 0.01f*x;
  q_out[i] = __expf(x - M);
}

// aggregation: 2-deep pipelined weighted gather (2 edges in flight per quad)
__global__ __launch_bounds__(256) void agg_k(const int* __restrict__ offs, const int* __restrict__ tgt_s,
    const float* __restrict__ w8, const float* __restrict__ x, float* __restrict__ pre, int nbase){
  int wid  = nbase + ((blockIdx.x*blockDim.x + threadIdx.x) >> 6);
  int lane = threadIdx.x & 63;
  int quad = lane >> 4, l16 = lane & 15;
  int b  = offs[wid];
  int e2 = offs[wid+1];
  float  den[8];
  float4 num[8];
#pragma unroll
  for(int h=0;h<8;h++){ den[h] = 0.f; num[h] = make_float4(0.f,0.f,0.f,0.f); }
  const float4* X4 = (const float4*)x;
  int i = b + quad;
  for(; i + 4 < e2; i += 8){
    int t0 = tgt_s[i];
    int t1 = tgt_s[i+4];
    float4 wa0 = ((const float4*)w8)[(size_t)i*2];
    float4 wb0 = ((const float4*)w8)[(size_t)i*2+1];
    float4 wa1 = ((const float4*)w8)[(size_t)(i+4)*2];
    float4 wb1 = ((const float4*)w8)[(size_t)(i+4)*2+1];
    float4 xv0 = X4[(size_t)t0*16 + l16];
    float4 xv1 = X4[(size_t)t1*16 + l16];
    float wv0[8] = {wa0.x,wa0.y,wa0.z,wa0.w, wb0.x,wb0.y,wb0.z,wb0.w};
    float wv1[8] = {wa1.x,wa1.y,wa1.z,wa1.w, wb1.x,wb1.y,wb1.z,wb1.w};
#pragma unroll
    for(int h=0;h<8;h++){
      den[h]   += wv0[h] + wv1[h];
      num[h].x = fmaf(wv0[h],xv0.x, fmaf(wv1[h],xv1.x, num[h].x));
      num[h].y = fmaf(wv0[h],xv0.y, fmaf(wv1[h],xv1.y, num[h].y));
      num[h].z = fmaf(wv0[h],xv0.z, fmaf(wv1[h],xv1.z, num[h].z));
      num[h].w = fmaf(wv0[h],xv0.w, fmaf(wv1[h],xv1.w, num[h].w));
    }
  }
  if(i < e2){
    int t = tgt_s[i];
    float4 wa = ((const float4*)w8)[(size_t)i*2];
    float4 wb = ((const float4*)w8)[(size_t)i*2+1];
    float4 xv = X4[(size_t)t*16 + l16];
    float wv[8] = {wa.x,wa.y,wa.z,wa.w, wb.x,wb.y,wb.z,wb.w};
#pragma unroll
    for(int h=0;h<8;h++){
      den[h]   += wv[h];
      num[h].x = fmaf(wv[h],xv.x,num[h].x); num[h].y = fmaf(wv[h],xv.y,num[h].y);
      num[h].z = fmaf(wv[h],xv.z,num[h].z); num[h].w = fmaf(wv[h],xv.w,num[h].w);
    }
  }
#pragma unroll
  for(int h=0;h<8;h++){
    den[h]   += __shfl_xor(den[h],16,64);   den[h]   += __shfl_xor(den[h],32,64);
    num[h].x += __shfl_xor(num[h].x,16,64); num[h].x += __shfl_xor(num[h].x,32,64);
    num[h].y += __shfl_xor(num[h].y,16,64); num[h].y += __shfl_xor(num[h].y,32,64);
    num[h].z += __shfl_xor(num[h].z,16,64); num[h].z += __shfl_xor(num[h].z,32,64);
    num[h].w += __shfl_xor(num[h].w,16,64); num[h].w += __shfl_xor(num[h].w,32,64);
  }
  float* dst = pre + (size_t)(wid - nbase)*512;
#pragma unroll
  for(int k=0;k<2;k++){
    int h = 2*quad + k;
    float invd = (den[h] > 0.f) ? 1.0f/den[h] : 0.f;
    float4 o = make_float4(num[h].x*invd, num[h].y*invd, num[h].z*invd, num[h].w*invd);
    ((float4*)(dst + h*64))[l16] = o;
  }
}

// transform v6.1: v6 + float4 weight staging (fewer staging ops in the serial chain)
__global__ __launch_bounds__(256) void transform_k(const float* __restrict__ pre,
                                                   const float* __restrict__ gat_W,
                                                   const float* __restrict__ outW,
                                                   float* __restrict__ h2p,   // [2][NN][64]
                                                   int nbase, int cn){
  __shared__ float pz[64*68];
  __shared__ float Wl[4096];
  __shared__ float Ol[4096];
  int tid = threadIdx.x;
  int n0  = blockIdx.x * 64;
  int g   = blockIdx.y;
  h2p += (size_t)g * NN * 64;
  int a   = tid >> 4;
  int b   = tid & 15;
  float outacc[16];
#pragma unroll
  for(int i=0;i<16;i++) outacc[i] = 0.f;
#pragma unroll 1
  for(int hh=0; hh<4; hh++){
    int h = g*4 + hh;
    __syncthreads();
    const float4* Wg = (const float4*)(gat_W + (size_t)h*4096);
    const float4* Og = (const float4*)(outW  + (size_t)h*4096);
#pragma unroll
    for(int r4=0;r4<4;r4++){
      int f4 = r4*256 + tid;
      ((float4*)Wl)[f4] = Wg[f4];
      ((float4*)Ol)[f4] = Og[f4];
    }
#pragma unroll 1
    for(int r=0;r<16;r++){
      int flat = r*256 + tid;
      int n = flat >> 6, j = flat & 63;
      int gn = n0 + n;
      pz[j*68 + n] = (gn < cn) ? pre[(size_t)gn*512 + h*64 + j] : 0.f;
    }
    __syncthreads();
    float v[16];
#pragma unroll
    for(int i=0;i<16;i++) v[i] = 0.f;
#pragma unroll 4
    for(int j=0;j<64;j++){
      float4 pn = *(const float4*)&pz[j*68 + a*4];
      float4 wc = *(const float4*)&Wl[j*64 + b*4];
#pragma unroll
      for(int na=0;na<4;na++){
        float pv = (&pn.x)[na];
        v[na*4+0] = fmaf(pv, wc.x, v[na*4+0]);
        v[na*4+1] = fmaf(pv, wc.y, v[na*4+1]);
        v[na*4+2] = fmaf(pv, wc.z, v[na*4+2]);
        v[na*4+3] = fmaf(pv, wc.w, v[na*4+3]);
      }
    }
    __syncthreads();
#pragma unroll
    for(int cb=0;cb<4;cb++){
      float4 z4;
#pragma unroll
      for(int na=0;na<4;na++){
        float z  = (v[na*4+cb] > 0.f) ? v[na*4+cb] : expm1f(v[na*4+cb]);
        float z2 = (z > 0.f) ? z : expm1f(z);
        (&z4.x)[na] = z2;
      }
      *(float4*)&pz[(b*4+cb)*68 + a*4] = z4;
    }
    __syncthreads();
#pragma unroll 4
    for(int c=0;c<64;c++){
      float4 zn = *(const float4*)&pz[c*68 + a*4];
      float4 oc = *(const float4*)&Ol[c*64 + b*4];
#pragma unroll
      for(int na=0;na<4;na++){
        float zv = (&zn.x)[na];
        outacc[na*4+0] = fmaf(zv, oc.x, outacc[na*4+0]);
        outacc[na*4+1] = fmaf(zv, oc.y, outacc[na*4+1]);
        outacc[na*4+2] = fmaf(zv, oc.z, outacc[na*4+2]);
        outacc[na*4+3] = fmaf(zv, oc.w, outacc[na*4+3]);
      }
    }
  }
#pragma unroll
  for(int na=0;na<4;na++){
    int nl = n0 + a*4 + na;
    if(nl < cn){
      float4 o = make_float4(outacc[na*4+0], outacc[na*4+1], outacc[na*4+2], outacc[na*4+3]);
      *(float4*)&h2p[(size_t)(nbase + nl)*64 + b*4] = o;
    }
  }
}

// finalize: h2f = p0+p1 (h2f aliases dead x); ps_o/pt_o
__global__ __launch_bounds__(256) void finalize_po(const float* __restrict__ p0, const float* __restrict__ p1,
                                                   const float* __restrict__ out_a, float* __restrict__ h2f,
                                                   float* __restrict__ ps_o, float* __restrict__ pt_o){
  int wid  = (blockIdx.x*blockDim.x + threadIdx.x) >> 6;
  int lane = threadIdx.x & 63;
  if(wid >= NN) return;
  float v = p0[(size_t)wid*64 + lane] + p1[(size_t)wid*64 + lane];
  float ps = wsum(v * out_a[lane]);
  float pt = wsum(v * out_a[64+lane]);
  if(lane == 0){ ps_o[wid] = ps; pt_o[wid] = pt; }
  h2f[(size_t)wid*64 + lane] = v;
}

// output aggregation: 2-deep pipelined gather + log_softmax
__global__ __launch_bounds__(256) void agg_out(const int* __restrict__ offs, const int* __restrict__ tgt_s,
                                               const float* __restrict__ w_out, const float* __restrict__ h2f,
                                               float* __restrict__ dout){
  int wid  = (blockIdx.x*blockDim.x + threadIdx.x) >> 6;
  int lane = threadIdx.x & 63;
  if(wid >= NN) return;
  int quad = lane >> 4, l16 = lane & 15;
  int b  = offs[wid];
  int e2 = offs[wid+1];
  const float4* H4 = (const float4*)h2f;
  float4 num = make_float4(0.f,0.f,0.f,0.f);
  float den = 0.f;
  int i = b + quad;
  for(; i + 4 < e2; i += 8){
    int t0 = tgt_s[i];
    int t1 = tgt_s[i+4];
    float w0 = w_out[i];
    float w1 = w_out[i+4];
    float4 h0 = H4[(size_t)t0*16 + l16];
    float4 h1 = H4[(size_t)t1*16 + l16];
    den += w0 + w1;
    num.x = fmaf(w0,h0.x, fmaf(w1,h1.x, num.x));
    num.y = fmaf(w0,h0.y, fmaf(w1,h1.y, num.y));
    num.z = fmaf(w0,h0.z, fmaf(w1,h1.z, num.z));
    num.w = fmaf(w0,h0.w, fmaf(w1,h1.w, num.w));
  }
  if(i < e2){
    int t = tgt_s[i];
    float w = w_out[i];
    float4 hv = H4[(size_t)t*16 + l16];
    den += w;
    num.x = fmaf(w,hv.x,num.x); num.y = fmaf(w,hv.y,num.y);
    num.z = fmaf(w,hv.z,num.z); num.w = fmaf(w,hv.w,num.w);
  }
  den   += __shfl_xor(den,16,64);   den   += __shfl_xor(den,32,64);
  num.x += __shfl_xor(num.x,16,64); num.x += __shfl_xor(num.x,32,64);
  num.y += __shfl_xor(num.y,16,64); num.y += __shfl_xor(num.y,32,64);
  num.z += __shfl_xor(num.z,16,64); num.z += __shfl_xor(num.z,32,64);
  num.w += __shfl_xor(num.w,16,64); num.w += __shfl_xor(num.w,32,64);
  float inv = (den > 0.f) ? 1.0f/den : 0.f;
  float z[4];
  float mloc = -3.0e38f;
#pragma unroll
  for(int k=0;k<4;k++){
    float hp = ((&num.x)[k]) * inv;
    z[k] = (hp > 0.f) ? hp : expm1f(hp);
    mloc = fmaxf(mloc, z[k]);
  }
#pragma unroll
  for(int msk=1; msk<16; msk<<=1) mloc = fmaxf(mloc, __shfl_xor(mloc,msk,64));
  float ssum = 0.f;
#pragma unroll
  for(int k=0;k<4;k++) ssum += __expf(z[k] - mloc);
#pragma unroll
  for(int msk=1; msk<16; msk<<=1) ssum += __shfl_xor(ssum,msk,64);
  float lse = mloc + logf(ssum);
  if(quad == 0){
    float4 o = make_float4(z[0]-lse, z[1]-lse, z[2]-lse, z[3]-lse);
    ((float4*)dout)[(size_t)wid*16 + l16] = o;
  }
}

extern "C" void kernel_launch(void* const* d_in, const int* in_sizes, int n_in,
                              void* d_out, int out_size, void* d_ws, size_t ws_size,
                              hipStream_t stream) {
  const float* X         = (const float*)d_in[0];
  const float* edge_attr = (const float*)d_in[1];
  const int*   edge_index= (const int*)d_in[2];
  const float* w_node    = (const float*)d_in[4];
  const float* b_node    = (const float*)d_in[5];
  const float* g_node    = (const float*)d_in[6];
  const float* beta_node = (const float*)d_in[7];
  const float* w_edge    = (const float*)d_in[8];
  const float* b_edge    = (const float*)d_in[9];
  const float* g_edge    = (const float*)d_in[10];
  const float* beta_edge = (const float*)d_in[11];
  const float* gat_W     = (const float*)d_in[12];
  const float* gat_a     = (const float*)d_in[13];
  const float* out_W     = (const float*)d_in[14];
  const float* out_a     = (const float*)d_in[15];
  float* dout = (float*)d_out;

  const int* src = edge_index;
  const int* tgt = edge_index + EE;

  char* base = (char*)d_ws;
  size_t off = 0;
  auto take = [&](size_t bytes)->char*{ char* p = base + off; off += (bytes + 31) & ~(size_t)31; return p; };
  int*      counts = (int*)     take((size_t)NN*4);
  int*      cursor = (int*)     take((size_t)NN*4);
  int*      offs   = (int*)     take((size_t)(NN+1)*4);
  int*      bsum   = (int*)     take(256*4);
  int*      bpre   = (int*)     take(256*4);
  unsigned* mx     = (unsigned*)take(64*4);
  float*    ps_o   = (float*)   take((size_t)NN*4);
  float*    pt_o   = (float*)   take((size_t)NN*4);
  float*    cdir   = (float*)   take(1024*4);
  int*      rank   = (int*)     take((size_t)EE*4);
  int*      tgt_s  = (int*)     take((size_t)EE*4);
  int*      src_s  = (int*)     take((size_t)EE*4);
  float*    ps8    = (float*)   take((size_t)NN*8*4);
  float*    pt8    = (float*)   take((size_t)NN*8*4);
  float*    x      = (float*)   take((size_t)NN*64*4);
  float*    h2p    = (float*)   take((size_t)2*NN*64*4);  // [2][NN][64] partials
  float*    q8     = (float*)   take((size_t)EE*8*4);
  float*    q_out  = (float*)   take((size_t)EE*4);
  float*    pre    = (float*)   take((size_t)HALF*512*4);
  float*    h2f    = x;   // alias: x dead after last agg_k; finalize writes h2f after
  // total ~142 MB

  const int NBLK_N  = (NN*64 + 255)/256;
  const int NBLK_E  = (EE + 255)/256;
  const int NBLK_S  = (NN + 255)/256;
  const int NBLK_A  = HALF/4;
  const int NBLK_T  = (HALF + 63)/64;

  zero_k   <<<NBLK_S, 256, 0, stream>>>(counts, cursor, mx);
  cvec_k   <<<8,       64, 0, stream>>>(gat_W, gat_a, cdir);
  node_mlp <<<NBLK_N, 256, 0, stream>>>(X, w_node, b_node, g_node, beta_node, cdir, x, ps8, pt8);
  hist_k   <<<NBLK_E, 256, 0, stream>>>(src, counts);
  scan1_k  <<<NBLK_S, 256, 0, stream>>>(counts, bsum);
  scan2_k  <<<1,      256, 0, stream>>>(bsum, bpre, offs);
  scan3_k  <<<NBLK_S, 256, 0, stream>>>(counts, bpre, offs);
  scatter_k<<<NBLK_E, 256, 0, stream>>>(src, tgt, offs, cursor, rank, tgt_s, src_s);
  edge_mlp_q<<<NBLK_E,256, 0, stream>>>(rank, edge_attr, w_edge, b_edge, g_edge, beta_edge,
                                        gat_a, out_a, q8, q_out);
  maxq_k   <<<1024,   256, 0, stream>>>(q8, q_out, mx);
  maxp_k   <<<128,    256, 0, stream>>>(ps8, pt8, mx);
  score_k  <<<NBLK_E, 256, 0, stream>>>(src_s, tgt_s, ps8, pt8, mx, q8);

  for(int half=0; half<2; half++){
    int nbase = half*HALF;
    agg_k<<<NBLK_A, 256, 0, stream>>>(offs, tgt_s, q8, x, pre, nbase);
    dim3 tg((unsigned)NBLK_T, 2);
    transform_k<<<tg, 256, 0, stream>>>(pre, gat_W, out_W, h2p, nbase, HALF);
  }

  finalize_po<<<NBLK_N, 256, 0, stream>>>(h2p, h2p + (size_t)NN*64, out_a, h2f, ps_o, pt_o);
  maxpo_k    <<<128,  256, 0, stream>>>(ps_o, pt_o, mx);
  score_out_k<<<NBLK_E,256, 0, stream>>>(src_s, tgt_s, ps_o, pt_o, mx, q_out);
  agg_out    <<<NBLK_N,256, 0, stream>>>(offs, tgt_s, q_out, h2f, dout);
}

// Round 15
// 791.474 us; speedup vs baseline: 1.0886x; 1.0886x over previous
//
#include <hip/hip_runtime.h>

#define NN 50000
#define EE 1000000
#define HALF 25000

__device__ __forceinline__ float wsum(float v){
#pragma unroll
  for(int m=1;m<64;m<<=1) v += __shfl_xor(v,m,64);
  return v;
}
__device__ __forceinline__ unsigned encf(float f){
  unsigned u = __float_as_uint(f);
  return (u & 0x80000000u) ? ~u : (u | 0x80000000u);
}
__device__ __forceinline__ float decf(unsigned u){
  u = (u & 0x80000000u) ? (u & 0x7fffffffu) : ~u;
  return __uint_as_float(u);
}

__global__ __launch_bounds__(256) void zero_k(int* counts, int* cursor, unsigned* mx){
  int i = blockIdx.x*blockDim.x + threadIdx.x;
  if(i < NN){ counts[i] = 0; cursor[i] = 0; }
  if(i < 64) mx[i] = 0u;
}

__global__ __launch_bounds__(64) void cvec_k(const float* __restrict__ gat_W, const float* __restrict__ gat_a,
                                             float* __restrict__ cdir){
  int h = blockIdx.x, k = threadIdx.x;
  const float* W = gat_W + (size_t)h*64*64;
  const float* a = gat_a + (size_t)h*192;
  float cs = 0.f, ct = 0.f;
#pragma unroll
  for(int j=0;j<64;j++){ float wv = W[k*64+j]; cs += wv*a[j]; ct += wv*a[64+j]; }
  cdir[h*64 + k]       = cs;
  cdir[512 + h*64 + k] = ct;
}

// node MLP fused with per-head projections ps8/pt8
__global__ __launch_bounds__(256) void node_mlp(const float* __restrict__ X, const float* __restrict__ w,
                                                const float* __restrict__ b, const float* __restrict__ g,
                                                const float* __restrict__ beta, const float* __restrict__ cdir,
                                                float* __restrict__ x, float* __restrict__ ps8,
                                                float* __restrict__ pt8){
  int wid  = (blockIdx.x*blockDim.x + threadIdx.x) >> 6;
  int lane = threadIdx.x & 63;
  if(wid >= NN) return;
  float acc = b[lane];
#pragma unroll
  for(int k=0;k<16;k++) acc += X[wid*16+k] * w[k*64+lane];
  float mu  = wsum(acc) * (1.0f/64.0f);
  float d   = acc - mu;
  float var = wsum(d*d) * (1.0f/64.0f);
  float y   = d * rsqrtf(var + 1e-5f) * g[lane] + beta[lane];
  float xv  = fmaxf(y, 0.0f);
  x[(size_t)wid*64 + lane] = xv;
#pragma unroll 1
  for(int h=0;h<8;h++){
    float a = wsum(xv * cdir[h*64+lane]);
    float c = wsum(xv * cdir[512 + h*64+lane]);
    if(lane == 0){ ps8[wid*8+h] = a; pt8[wid*8+h] = c; }
  }
}

__global__ __launch_bounds__(256) void hist_k(const int* __restrict__ src, int* __restrict__ counts){
  int e = blockIdx.x*blockDim.x + threadIdx.x;
  if(e < EE){
    int s = src[e];
    if((unsigned)s >= NN) s = 0;
    atomicAdd(&counts[s], 1);
  }
}

__global__ __launch_bounds__(256) void scan1_k(const int* __restrict__ counts, int* __restrict__ bsum){
  int i = blockIdx.x*256 + threadIdx.x;
  int v = (i < NN) ? counts[i] : 0;
  int s = v;
#pragma unroll
  for(int m=1;m<64;m<<=1) s += __shfl_xor(s,m,64);
  __shared__ int sm[4];
  if((threadIdx.x & 63) == 0) sm[threadIdx.x>>6] = s;
  __syncthreads();
  if(threadIdx.x == 0) bsum[blockIdx.x] = sm[0]+sm[1]+sm[2]+sm[3];
}

__global__ __launch_bounds__(256) void scan2_k(const int* __restrict__ bsum, int* __restrict__ bpre,
                                               int* __restrict__ offs){
  const int NB = (NN + 255)/256;
  int t = threadIdx.x;
  __shared__ int sm[256];
  int v = (t < NB) ? bsum[t] : 0;
  sm[t] = v; __syncthreads();
  for(int off=1; off<256; off<<=1){
    int u = (t >= off) ? sm[t-off] : 0;
    __syncthreads();
    sm[t] += u;
    __syncthreads();
  }
  if(t < NB) bpre[t] = sm[t] - v;
  if(t == 0) offs[NN] = EE;
}

__global__ __launch_bounds__(256) void scan3_k(const int* __restrict__ counts, const int* __restrict__ bpre,
                                               int* __restrict__ offs){
  int i = blockIdx.x*256 + threadIdx.x;
  int t = threadIdx.x;
  __shared__ int sm[256];
  int v = (i < NN) ? counts[i] : 0;
  sm[t] = v; __syncthreads();
  for(int off=1; off<256; off<<=1){
    int u = (t >= off) ? sm[t-off] : 0;
    __syncthreads();
    sm[t] += u;
    __syncthreads();
  }
  if(i < NN) offs[i] = bpre[blockIdx.x] + sm[t] - v;
}

__global__ __launch_bounds__(256) void scatter_k(const int* __restrict__ src, const int* __restrict__ tgt,
                                                 const int* __restrict__ offs, int* __restrict__ cursor,
                                                 int* __restrict__ rank, int* __restrict__ tgt_s,
                                                 int* __restrict__ src_s){
  int e = blockIdx.x*blockDim.x + threadIdx.x;
  if(e < EE){
    int s = src[e];
    if((unsigned)s >= NN) s = 0;
    int pos = offs[s] + atomicAdd(&cursor[s], 1);
    rank[e] = pos;
    int t = tgt[e];
    if((unsigned)t >= NN) t = 0;
    tgt_s[pos] = t;
    src_s[pos] = s;
  }
}

// edge MLP v2 (validated R10): LDS-staged weights
__global__ __launch_bounds__(256) void edge_mlp_q(const int* __restrict__ rank, const float* __restrict__ ea,
                                                  const float* __restrict__ w, const float* __restrict__ b,
                                                  const float* __restrict__ g, const float* __restrict__ beta,
                                                  const float* __restrict__ gat_a, const float* __restrict__ out_a,
                                                  float* __restrict__ q8, float* __restrict__ q_out){
  __shared__ float wle[512];
  __shared__ float ble[64], gle[64], bbe[64];
  __shared__ float ale[64*12];
  int tid = threadIdx.x;
  for(int idx=tid; idx<512; idx+=256){ int j=idx>>3, k=idx&7; wle[idx] = w[k*64+j]; }
  if(tid < 64){
    ble[tid] = b[tid]; gle[tid] = g[tid]; bbe[tid] = beta[tid];
#pragma unroll
    for(int r=0;r<8;r++) ale[tid*12+r] = gat_a[r*192 + 128 + tid];
    ale[tid*12+8] = out_a[128 + tid];
  }
  __syncthreads();
  int e = blockIdx.x*blockDim.x + tid;
  if(e >= EE) return;
  float4 ia = ((const float4*)ea)[(size_t)e*2];
  float4 ib = ((const float4*)ea)[(size_t)e*2+1];
  float y[64];
#pragma unroll
  for(int j=0;j<64;j++){
    float4 w0 = *(const float4*)&wle[j*8];
    float4 w1 = *(const float4*)&wle[j*8+4];
    float acc = ble[j];
    acc = fmaf(ia.x,w0.x, fmaf(ia.y,w0.y, fmaf(ia.z,w0.z, fmaf(ia.w,w0.w, acc))));
    acc = fmaf(ib.x,w1.x, fmaf(ib.y,w1.y, fmaf(ib.z,w1.z, fmaf(ib.w,w1.w, acc))));
    y[j] = acc;
  }
  float mu = 0.f;
#pragma unroll
  for(int j=0;j<64;j++) mu += y[j];
  mu *= (1.0f/64.0f);
  float var = 0.f;
#pragma unroll
  for(int j=0;j<64;j++){ float d = y[j]-mu; var += d*d; }
  var *= (1.0f/64.0f);
  float inv = rsqrtf(var + 1e-5f);
#pragma unroll
  for(int j=0;j<64;j++) y[j] = fmaxf((y[j]-mu)*inv*gle[j] + bbe[j], 0.0f);
  float qv[9];
#pragma unroll
  for(int r=0;r<9;r++) qv[r] = 0.f;
#pragma unroll
  for(int j=0;j<64;j++){
    float4 a0 = *(const float4*)&ale[j*12];
    float4 a1 = *(const float4*)&ale[j*12+4];
    float a8  = ale[j*12+8];
    float yj = y[j];
    qv[0]=fmaf(yj,a0.x,qv[0]); qv[1]=fmaf(yj,a0.y,qv[1]); qv[2]=fmaf(yj,a0.z,qv[2]); qv[3]=fmaf(yj,a0.w,qv[3]);
    qv[4]=fmaf(yj,a1.x,qv[4]); qv[5]=fmaf(yj,a1.y,qv[5]); qv[6]=fmaf(yj,a1.z,qv[6]); qv[7]=fmaf(yj,a1.w,qv[7]);
    qv[8]=fmaf(yj,a8 ,qv[8]);
  }
  int r = rank[e];
  ((float4*)q8)[(size_t)r*2]   = make_float4(qv[0],qv[1],qv[2],qv[3]);
  ((float4*)q8)[(size_t)r*2+1] = make_float4(qv[4],qv[5],qv[6],qv[7]);
  q_out[r] = qv[8];
}

__global__ __launch_bounds__(256) void maxq_k(const float* __restrict__ q8, const float* __restrict__ q_out,
                                              unsigned* __restrict__ mx){
  float m[9];
#pragma unroll
  for(int r=0;r<9;r++) m[r] = -3.0e38f;
  for(int i = blockIdx.x*256 + threadIdx.x; i < EE; i += gridDim.x*256){
    float4 a = ((const float4*)q8)[(size_t)i*2];
    float4 c = ((const float4*)q8)[(size_t)i*2+1];
    m[0]=fmaxf(m[0],a.x); m[1]=fmaxf(m[1],a.y); m[2]=fmaxf(m[2],a.z); m[3]=fmaxf(m[3],a.w);
    m[4]=fmaxf(m[4],c.x); m[5]=fmaxf(m[5],c.y); m[6]=fmaxf(m[6],c.z); m[7]=fmaxf(m[7],c.w);
    m[8]=fmaxf(m[8], q_out[i]);
  }
#pragma unroll
  for(int r=0;r<9;r++)
#pragma unroll
    for(int msk=1;msk<64;msk<<=1) m[r] = fmaxf(m[r], __shfl_xor(m[r],msk,64));
  __shared__ float sm[4][9];
  int wv = threadIdx.x>>6, lane = threadIdx.x&63;
  if(lane == 0){
#pragma unroll
    for(int r=0;r<9;r++) sm[wv][r] = m[r];
  }
  __syncthreads();
  if(threadIdx.x < 9){
    int r = threadIdx.x;
    float v = fmaxf(fmaxf(sm[0][r],sm[1][r]), fmaxf(sm[2][r],sm[3][r]));
    atomicMax(&mx[r], encf(v));
  }
}

__global__ __launch_bounds__(256) void maxp_k(const float* __restrict__ ps8, const float* __restrict__ pt8,
                                              unsigned* __restrict__ mx){
  float m[16];
#pragma unroll
  for(int r=0;r<16;r++) m[r] = -3.0e38f;
  for(int i = blockIdx.x*256 + threadIdx.x; i < NN; i += gridDim.x*256){
    float4 a = ((const float4*)ps8)[(size_t)i*2];
    float4 c = ((const float4*)ps8)[(size_t)i*2+1];
    float4 d = ((const float4*)pt8)[(size_t)i*2];
    float4 e = ((const float4*)pt8)[(size_t)i*2+1];
    m[0]=fmaxf(m[0],a.x); m[1]=fmaxf(m[1],a.y); m[2]=fmaxf(m[2],a.z); m[3]=fmaxf(m[3],a.w);
    m[4]=fmaxf(m[4],c.x); m[5]=fmaxf(m[5],c.y); m[6]=fmaxf(m[6],c.z); m[7]=fmaxf(m[7],c.w);
    m[8]=fmaxf(m[8],d.x); m[9]=fmaxf(m[9],d.y); m[10]=fmaxf(m[10],d.z); m[11]=fmaxf(m[11],d.w);
    m[12]=fmaxf(m[12],e.x); m[13]=fmaxf(m[13],e.y); m[14]=fmaxf(m[14],e.z); m[15]=fmaxf(m[15],e.w);
  }
#pragma unroll
  for(int r=0;r<16;r++)
#pragma unroll
    for(int msk=1;msk<64;msk<<=1) m[r] = fmaxf(m[r], __shfl_xor(m[r],msk,64));
  __shared__ float sm[4][16];
  int wv = threadIdx.x>>6, lane = threadIdx.x&63;
  if(lane == 0){
#pragma unroll
    for(int r=0;r<16;r++) sm[wv][r] = m[r];
  }
  __syncthreads();
  if(threadIdx.x < 16){
    int r = threadIdx.x;
    float v = fmaxf(fmaxf(sm[0][r],sm[1][r]), fmaxf(sm[2][r],sm[3][r]));
    atomicMax(&mx[16+r], encf(v));
  }
}

__global__ __launch_bounds__(256) void maxpo_k(const float* __restrict__ ps_o, const float* __restrict__ pt_o,
                                               unsigned* __restrict__ mx){
  float m0 = -3.0e38f, m1 = -3.0e38f;
  for(int i = blockIdx.x*256 + threadIdx.x; i < NN; i += gridDim.x*256){
    m0 = fmaxf(m0, ps_o[i]); m1 = fmaxf(m1, pt_o[i]);
  }
#pragma unroll
  for(int msk=1;msk<64;msk<<=1){ m0=fmaxf(m0,__shfl_xor(m0,msk,64)); m1=fmaxf(m1,__shfl_xor(m1,msk,64)); }
  __shared__ float sm[4][2];
  int wv = threadIdx.x>>6, lane = threadIdx.x&63;
  if(lane == 0){ sm[wv][0]=m0; sm[wv][1]=m1; }
  __syncthreads();
  if(threadIdx.x < 2){
    int r = threadIdx.x;
    float v = fmaxf(fmaxf(sm[0][r],sm[1][r]), fmaxf(sm[2][r],sm[3][r]));
    atomicMax(&mx[32+r], encf(v));
  }
}

__global__ __launch_bounds__(256) void score_k(const int* __restrict__ src_s, const int* __restrict__ tgt_s,
                                               const float* __restrict__ ps8, const float* __restrict__ pt8,
                                               const unsigned* __restrict__ mx, float* __restrict__ q8){
  int i = blockIdx.x*256 + threadIdx.x;
  if(i >= EE) return;
  int s = src_s[i], t = tgt_s[i];
  float4 qa = ((const float4*)q8)[(size_t)i*2];
  float4 qb = ((const float4*)q8)[(size_t)i*2+1];
  float4 sa = ((const float4*)ps8)[(size_t)s*2];
  float4 sb = ((const float4*)ps8)[(size_t)s*2+1];
  float4 ta = ((const float4*)pt8)[(size_t)t*2];
  float4 tb = ((const float4*)pt8)[(size_t)t*2+1];
  float sv[8] = {qa.x+sa.x+ta.x, qa.y+sa.y+ta.y, qa.z+sa.z+ta.z, qa.w+sa.w+ta.w,
                 qb.x+sb.x+tb.x, qb.y+sb.y+tb.y, qb.z+sb.z+tb.z, qb.w+sb.w+tb.w};
  float wv[8];
#pragma unroll
  for(int h=0;h<8;h++){
    float B = decf(mx[h]) + decf(mx[16+h]) + decf(mx[24+h]);
    float M = (B > 0.f) ? B : 0.01f*B;
    float x = sv[h];
    x = (x > 0.f) ? x : 0.01f*x;
    wv[h] = __expf(x - M);
  }
  ((float4*)q8)[(size_t)i*2]   = make_float4(wv[0],wv[1],wv[2],wv[3]);
  ((float4*)q8)[(size_t)i*2+1] = make_float4(wv[4],wv[5],wv[6],wv[7]);
}

__global__ __launch_bounds__(256) void score_out_k(const int* __restrict__ src_s, const int* __restrict__ tgt_s,
                                                   const float* __restrict__ ps_o, const float* __restrict__ pt_o,
                                                   const unsigned* __restrict__ mx, float* __restrict__ q_out){
  int i = blockIdx.x*256 + threadIdx.x;
  if(i >= EE) return;
  float B = decf(mx[8]) + decf(mx[32]) + decf(mx[33]);
  float M = (B > 0.f) ? B : 0.01f*B;
  float x = ps_o[src_s[i]] + pt_o[tgt_s[i]] + q_out[i];
  x = (x > 0.f) ? x : 0.01f*x;
  q_out[i] = __expf(x - M);
}

// aggregation: R13 single-edge loop (validated; R14 2-deep pipeline regressed)
__global__ __launch_bounds__(256) void agg_k(const int* __restrict__ offs, const int* __restrict__ tgt_s,
    const float* __restrict__ w8, const float* __restrict__ x, float* __restrict__ pre, int nbase){
  int wid  = nbase + ((blockIdx.x*blockDim.x + threadIdx.x) >> 6);
  int lane = threadIdx.x & 63;
  int quad = lane >> 4, l16 = lane & 15;
  int b  = offs[wid];
  int e2 = offs[wid+1];
  float  den[8];
  float4 num[8];
#pragma unroll
  for(int h=0;h<8;h++){ den[h] = 0.f; num[h] = make_float4(0.f,0.f,0.f,0.f); }
  const float4* X4 = (const float4*)x;
  for(int i=b+quad; i<e2; i+=4){
    int t = tgt_s[i];
    float4 wa = ((const float4*)w8)[(size_t)i*2];
    float4 wb = ((const float4*)w8)[(size_t)i*2+1];
    float4 xv = X4[(size_t)t*16 + l16];
    float wv[8] = {wa.x,wa.y,wa.z,wa.w, wb.x,wb.y,wb.z,wb.w};
#pragma unroll
    for(int h=0;h<8;h++){
      den[h]   += wv[h];
      num[h].x = fmaf(wv[h],xv.x,num[h].x); num[h].y = fmaf(wv[h],xv.y,num[h].y);
      num[h].z = fmaf(wv[h],xv.z,num[h].z); num[h].w = fmaf(wv[h],xv.w,num[h].w);
    }
  }
#pragma unroll
  for(int h=0;h<8;h++){
    den[h]   += __shfl_xor(den[h],16,64);   den[h]   += __shfl_xor(den[h],32,64);
    num[h].x += __shfl_xor(num[h].x,16,64); num[h].x += __shfl_xor(num[h].x,32,64);
    num[h].y += __shfl_xor(num[h].y,16,64); num[h].y += __shfl_xor(num[h].y,32,64);
    num[h].z += __shfl_xor(num[h].z,16,64); num[h].z += __shfl_xor(num[h].z,32,64);
    num[h].w += __shfl_xor(num[h].w,16,64); num[h].w += __shfl_xor(num[h].w,32,64);
  }
  float* dst = pre + (size_t)(wid - nbase)*512;
#pragma unroll
  for(int k=0;k<2;k++){
    int h = 2*quad + k;
    float invd = (den[h] > 0.f) ? 1.0f/den[h] : 0.f;
    float4 o = make_float4(num[h].x*invd, num[h].y*invd, num[h].z*invd, num[h].w*invd);
    ((float4*)(dst + h*64))[l16] = o;
  }
}

// transform v6.2: float4 weight staging (R14) + float4 pre staging (4 iters, new)
__global__ __launch_bounds__(256) void transform_k(const float* __restrict__ pre,
                                                   const float* __restrict__ gat_W,
                                                   const float* __restrict__ outW,
                                                   float* __restrict__ h2p,   // [2][NN][64]
                                                   int nbase, int cn){
  __shared__ float pz[64*68];
  __shared__ float Wl[4096];
  __shared__ float Ol[4096];
  int tid = threadIdx.x;
  int n0  = blockIdx.x * 64;
  int g   = blockIdx.y;
  h2p += (size_t)g * NN * 64;
  int a   = tid >> 4;
  int b   = tid & 15;
  float outacc[16];
#pragma unroll
  for(int i=0;i<16;i++) outacc[i] = 0.f;
#pragma unroll 1
  for(int hh=0; hh<4; hh++){
    int h = g*4 + hh;
    __syncthreads();
    const float4* Wg = (const float4*)(gat_W + (size_t)h*4096);
    const float4* Og = (const float4*)(outW  + (size_t)h*4096);
#pragma unroll
    for(int r4=0;r4<4;r4++){
      int f4 = r4*256 + tid;
      ((float4*)Wl)[f4] = Wg[f4];
      ((float4*)Ol)[f4] = Og[f4];
    }
    // pre staging: float4 along j; idx -> n = idx>>4, j4 = idx&15
#pragma unroll
    for(int r4=0;r4<4;r4++){
      int idx = r4*256 + tid;
      int n = idx >> 4, j4 = idx & 15;
      int gn = n0 + n;
      float4 p = (gn < cn) ? *(const float4*)&pre[(size_t)gn*512 + h*64 + j4*4]
                           : make_float4(0.f,0.f,0.f,0.f);
      pz[(j4*4+0)*68 + n] = p.x;
      pz[(j4*4+1)*68 + n] = p.y;
      pz[(j4*4+2)*68 + n] = p.z;
      pz[(j4*4+3)*68 + n] = p.w;
    }
    __syncthreads();
    float v[16];
#pragma unroll
    for(int i=0;i<16;i++) v[i] = 0.f;
#pragma unroll 4
    for(int j=0;j<64;j++){
      float4 pn = *(const float4*)&pz[j*68 + a*4];
      float4 wc = *(const float4*)&Wl[j*64 + b*4];
#pragma unroll
      for(int na=0;na<4;na++){
        float pv = (&pn.x)[na];
        v[na*4+0] = fmaf(pv, wc.x, v[na*4+0]);
        v[na*4+1] = fmaf(pv, wc.y, v[na*4+1]);
        v[na*4+2] = fmaf(pv, wc.z, v[na*4+2]);
        v[na*4+3] = fmaf(pv, wc.w, v[na*4+3]);
      }
    }
    __syncthreads();
#pragma unroll
    for(int cb=0;cb<4;cb++){
      float4 z4;
#pragma unroll
      for(int na=0;na<4;na++){
        float z  = (v[na*4+cb] > 0.f) ? v[na*4+cb] : expm1f(v[na*4+cb]);
        float z2 = (z > 0.f) ? z : expm1f(z);
        (&z4.x)[na] = z2;
      }
      *(float4*)&pz[(b*4+cb)*68 + a*4] = z4;
    }
    __syncthreads();
#pragma unroll 4
    for(int c=0;c<64;c++){
      float4 zn = *(const float4*)&pz[c*68 + a*4];
      float4 oc = *(const float4*)&Ol[c*64 + b*4];
#pragma unroll
      for(int na=0;na<4;na++){
        float zv = (&zn.x)[na];
        outacc[na*4+0] = fmaf(zv, oc.x, outacc[na*4+0]);
        outacc[na*4+1] = fmaf(zv, oc.y, outacc[na*4+1]);
        outacc[na*4+2] = fmaf(zv, oc.z, outacc[na*4+2]);
        outacc[na*4+3] = fmaf(zv, oc.w, outacc[na*4+3]);
      }
    }
  }
#pragma unroll
  for(int na=0;na<4;na++){
    int nl = n0 + a*4 + na;
    if(nl < cn){
      float4 o = make_float4(outacc[na*4+0], outacc[na*4+1], outacc[na*4+2], outacc[na*4+3]);
      *(float4*)&h2p[(size_t)(nbase + nl)*64 + b*4] = o;
    }
  }
}

// finalize: h2f = p0+p1 (h2f aliases dead x); ps_o/pt_o
__global__ __launch_bounds__(256) void finalize_po(const float* __restrict__ p0, const float* __restrict__ p1,
                                                   const float* __restrict__ out_a, float* __restrict__ h2f,
                                                   float* __restrict__ ps_o, float* __restrict__ pt_o){
  int wid  = (blockIdx.x*blockDim.x + threadIdx.x) >> 6;
  int lane = threadIdx.x & 63;
  if(wid >= NN) return;
  float v = p0[(size_t)wid*64 + lane] + p1[(size_t)wid*64 + lane];
  float ps = wsum(v * out_a[lane]);
  float pt = wsum(v * out_a[64+lane]);
  if(lane == 0){ ps_o[wid] = ps; pt_o[wid] = pt; }
  h2f[(size_t)wid*64 + lane] = v;
}

// output aggregation: R13 single-edge loop + log_softmax
__global__ __launch_bounds__(256) void agg_out(const int* __restrict__ offs, const int* __restrict__ tgt_s,
                                               const float* __restrict__ w_out, const float* __restrict__ h2f,
                                               float* __restrict__ dout){
  int wid  = (blockIdx.x*blockDim.x + threadIdx.x) >> 6;
  int lane = threadIdx.x & 63;
  if(wid >= NN) return;
  int quad = lane >> 4, l16 = lane & 15;
  int b  = offs[wid];
  int e2 = offs[wid+1];
  const float4* H4 = (const float4*)h2f;
  float4 num = make_float4(0.f,0.f,0.f,0.f);
  float den = 0.f;
  for(int i=b+quad; i<e2; i+=4){
    int t = tgt_s[i];
    float w = w_out[i];
    float4 hv = H4[(size_t)t*16 + l16];
    den += w;
    num.x = fmaf(w,hv.x,num.x); num.y = fmaf(w,hv.y,num.y);
    num.z = fmaf(w,hv.z,num.z); num.w = fmaf(w,hv.w,num.w);
  }
  den   += __shfl_xor(den,16,64);   den   += __shfl_xor(den,32,64);
  num.x += __shfl_xor(num.x,16,64); num.x += __shfl_xor(num.x,32,64);
  num.y += __shfl_xor(num.y,16,64); num.y += __shfl_xor(num.y,32,64);
  num.z += __shfl_xor(num.z,16,64); num.z += __shfl_xor(num.z,32,64);
  num.w += __shfl_xor(num.w,16,64); num.w += __shfl_xor(num.w,32,64);
  float inv = (den > 0.f) ? 1.0f/den : 0.f;
  float z[4];
  float mloc = -3.0e38f;
#pragma unroll
  for(int k=0;k<4;k++){
    float hp = ((&num.x)[k]) * inv;
    z[k] = (hp > 0.f) ? hp : expm1f(hp);
    mloc = fmaxf(mloc, z[k]);
  }
#pragma unroll
  for(int msk=1; msk<16; msk<<=1) mloc = fmaxf(mloc, __shfl_xor(mloc,msk,64));
  float ssum = 0.f;
#pragma unroll
  for(int k=0;k<4;k++) ssum += __expf(z[k] - mloc);
#pragma unroll
  for(int msk=1; msk<16; msk<<=1) ssum += __shfl_xor(ssum,msk,64);
  float lse = mloc + logf(ssum);
  if(quad == 0){
    float4 o = make_float4(z[0]-lse, z[1]-lse, z[2]-lse, z[3]-lse);
    ((float4*)dout)[(size_t)wid*16 + l16] = o;
  }
}

extern "C" void kernel_launch(void* const* d_in, const int* in_sizes, int n_in,
                              void* d_out, int out_size, void* d_ws, size_t ws_size,
                              hipStream_t stream) {
  const float* X         = (const float*)d_in[0];
  const float* edge_attr = (const float*)d_in[1];
  const int*   edge_index= (const int*)d_in[2];
  const float* w_node    = (const float*)d_in[4];
  const float* b_node    = (const float*)d_in[5];
  const float* g_node    = (const float*)d_in[6];
  const float* beta_node = (const float*)d_in[7];
  const float* w_edge    = (const float*)d_in[8];
  const float* b_edge    = (const float*)d_in[9];
  const float* g_edge    = (const float*)d_in[10];
  const float* beta_edge = (const float*)d_in[11];
  const float* gat_W     = (const float*)d_in[12];
  const float* gat_a     = (const float*)d_in[13];
  const float* out_W     = (const float*)d_in[14];
  const float* out_a     = (const float*)d_in[15];
  float* dout = (float*)d_out;

  const int* src = edge_index;
  const int* tgt = edge_index + EE;

  char* base = (char*)d_ws;
  size_t off = 0;
  auto take = [&](size_t bytes)->char*{ char* p = base + off; off += (bytes + 31) & ~(size_t)31; return p; };
  int*      counts = (int*)     take((size_t)NN*4);
  int*      cursor = (int*)     take((size_t)NN*4);
  int*      offs   = (int*)     take((size_t)(NN+1)*4);
  int*      bsum   = (int*)     take(256*4);
  int*      bpre   = (int*)     take(256*4);
  unsigned* mx     = (unsigned*)take(64*4);
  float*    ps_o   = (float*)   take((size_t)NN*4);
  float*    pt_o   = (float*)   take((size_t)NN*4);
  float*    cdir   = (float*)   take(1024*4);
  int*      rank   = (int*)     take((size_t)EE*4);
  int*      tgt_s  = (int*)     take((size_t)EE*4);
  int*      src_s  = (int*)     take((size_t)EE*4);
  float*    ps8    = (float*)   take((size_t)NN*8*4);
  float*    pt8    = (float*)   take((size_t)NN*8*4);
  float*    x      = (float*)   take((size_t)NN*64*4);
  float*    h2p    = (float*)   take((size_t)2*NN*64*4);  // [2][NN][64] partials
  float*    q8     = (float*)   take((size_t)EE*8*4);
  float*    q_out  = (float*)   take((size_t)EE*4);
  float*    pre    = (float*)   take((size_t)HALF*512*4);
  float*    h2f    = x;   // alias: x dead after last agg_k; finalize writes h2f after
  // total ~142 MB

  const int NBLK_N  = (NN*64 + 255)/256;
  const int NBLK_E  = (EE + 255)/256;
  const int NBLK_S  = (NN + 255)/256;
  const int NBLK_A  = HALF/4;
  const int NBLK_T  = (HALF + 63)/64;

  zero_k   <<<NBLK_S, 256, 0, stream>>>(counts, cursor, mx);
  cvec_k   <<<8,       64, 0, stream>>>(gat_W, gat_a, cdir);
  node_mlp <<<NBLK_N, 256, 0, stream>>>(X, w_node, b_node, g_node, beta_node, cdir, x, ps8, pt8);
  hist_k   <<<NBLK_E, 256, 0, stream>>>(src, counts);
  scan1_k  <<<NBLK_S, 256, 0, stream>>>(counts, bsum);
  scan2_k  <<<1,      256, 0, stream>>>(bsum, bpre, offs);
  scan3_k  <<<NBLK_S, 256, 0, stream>>>(counts, bpre, offs);
  scatter_k<<<NBLK_E, 256, 0, stream>>>(src, tgt, offs, cursor, rank, tgt_s, src_s);
  edge_mlp_q<<<NBLK_E,256, 0, stream>>>(rank, edge_attr, w_edge, b_edge, g_edge, beta_edge,
                                        gat_a, out_a, q8, q_out);
  maxq_k   <<<1024,   256, 0, stream>>>(q8, q_out, mx);
  maxp_k   <<<128,    256, 0, stream>>>(ps8, pt8, mx);
  score_k  <<<NBLK_E, 256, 0, stream>>>(src_s, tgt_s, ps8, pt8, mx, q8);

  for(int half=0; half<2; half++){
    int nbase = half*HALF;
    agg_k<<<NBLK_A, 256, 0, stream>>>(offs, tgt_s, q8, x, pre, nbase);
    dim3 tg((unsigned)NBLK_T, 2);
    transform_k<<<tg, 256, 0, stream>>>(pre, gat_W, out_W, h2p, nbase, HALF);
  }

  finalize_po<<<NBLK_N, 256, 0, stream>>>(h2p, h2p + (size_t)NN*64, out_a, h2f, ps_o, pt_o);
  maxpo_k    <<<128,  256, 0, stream>>>(ps_o, pt_o, mx);
  score_out_k<<<NBLK_E,256, 0, stream>>>(src_s, tgt_s, ps_o, pt_o, mx, q_out);
  agg_out    <<<NBLK_N,256, 0, stream>>>(offs, tgt_s, q_out, h2f, dout);
}